// Round 8
// baseline (271.004 us; speedup 1.0000x reference)
//
#include <hip/hip_runtime.h>
#include <hip/hip_bf16.h>

#define NS 512
#define NV 32000
#define NB 16
#define NT 128

#ifndef __has_builtin
#define __has_builtin(x) 0
#endif

typedef int v8i __attribute__((ext_vector_type(8)));
typedef float v4f __attribute__((ext_vector_type(4)));

// ---------------------------------------------------------------------------
// e4m3fn (OCP) encode, x >= 0.
// ---------------------------------------------------------------------------
__device__ inline unsigned enc_e4m3(float x) {
    x = fminf(x, 448.0f);
    unsigned u = __float_as_uint(x);
    if (x < 0.015625f) {
        return (unsigned)(int)rintf(x * 512.0f);
    }
    unsigned u2 = u + 0x7FFFFu + ((u >> 20) & 1u);
    return (((u2 >> 23) - 120u) << 3) | ((u2 >> 20) & 7u);
}

__device__ inline unsigned pack4_e4m3(float a, float b, float c, float d) {
#if __has_builtin(__builtin_amdgcn_cvt_pk_fp8_f32)
    int v = __builtin_amdgcn_cvt_pk_fp8_f32(a, b, 0, false);
    v = __builtin_amdgcn_cvt_pk_fp8_f32(c, d, v, true);
    return (unsigned)v;
#else
    return enc_e4m3(a) | (enc_e4m3(b) << 8) | (enc_e4m3(c) << 16) | (enc_e4m3(d) << 24);
#endif
}

// low byte only (bytes 1-3 zero): one cvt_pk instead of two.
__device__ inline unsigned pack1_e4m3(float a) {
#if __has_builtin(__builtin_amdgcn_cvt_pk_fp8_f32)
    return (unsigned)__builtin_amdgcn_cvt_pk_fp8_f32(a, 0.f, 0, false) & 0xFFFFu;
#else
    return enc_e4m3(a);
#endif
}

// DPP all-lane butterfly reduce within each row of 16 lanes.
#define DPPMAX(x, ctrl) \
    x = fmaxf(x, __int_as_float(__builtin_amdgcn_mov_dpp(__float_as_int(x), ctrl, 0xF, 0xF, true)))
#define DPPADD(x, ctrl) \
    x = x + __int_as_float(__builtin_amdgcn_mov_dpp(__float_as_int(x), ctrl, 0xF, 0xF, true))

#define UMX(a, b) ((a) > (b) ? (a) : (b))

__device__ inline unsigned bytemax8(unsigned a, unsigned b) {
    unsigned m0 = UMX(a & 255u, b & 255u);
    unsigned m1 = UMX((a >> 8) & 255u, (b >> 8) & 255u);
    unsigned m2 = UMX((a >> 16) & 255u, (b >> 16) & 255u);
    unsigned m3 = UMX(a >> 24, b >> 24);
    return UMX(UMX(m0, m1), UMX(m2, m3));
}

// ---------------------------------------------------------------------------
// K1a: per-state logZ over vocab + emission gather, COALESCED store to
// em_lin_T[s][j] = exp(em[s][ids_j]) / Z_s * 2^-18.
// ---------------------------------------------------------------------------
__global__ __launch_bounds__(256) void k_emtok_T(
    const float* __restrict__ em, const int* __restrict__ ids,
    float* __restrict__ em_lin_T)
{
    const int s   = blockIdx.x;
    const int tid = threadIdx.x;
    const float* row = em + (size_t)s * NV;

    int idv[8];
#pragma unroll
    for (int k = 0; k < 8; ++k) idv[k] = ids[tid + 256 * k];
    float g[8];
#pragma unroll
    for (int k = 0; k < 8; ++k) g[k] = row[idv[k]];

    float sum = 0.f;
    const float4* row4 = (const float4*)row;
#pragma unroll 4
    for (int i = 0; i < 31; ++i) {
        float4 v = row4[tid + 256 * i];
        sum += __expf(v.x) + __expf(v.y) + __expf(v.z) + __expf(v.w);
    }
    sum += __expf(row[31744 + tid]);

#pragma unroll
    for (int off = 32; off; off >>= 1) sum += __shfl_down(sum, off);
    __shared__ float red[4];
    __shared__ float s_scale;
    if ((tid & 63) == 0) red[tid >> 6] = sum;
    __syncthreads();
    if (tid == 0) s_scale = (1.0f / ((red[0] + red[1]) + (red[2] + red[3]))) * 0x1p-18f;
    __syncthreads();
    const float scale = s_scale;

#pragma unroll
    for (int k = 0; k < 8; ++k)
        em_lin_T[(size_t)s * (NB * NT) + tid + 256 * k] = __expf(g[k]) * scale;
}

// ---------------------------------------------------------------------------
// K1b: transpose em_lin_T [512][2048] -> em_lin [2048][512], with the state
// dimension PERMUTED so k_scan (4-wave layout) reads its 8 per-thread
// emission values as two float4s:
//   state s = 128w + 16nt + lc  ->  pos = 128w + lc*8 + nt
//   perm2(s) = (s & ~127) | ((s & 15) << 3) | ((s >> 4) & 7)
// ---------------------------------------------------------------------------
__global__ __launch_bounds__(256) void k_tr(
    const float* __restrict__ emT, float* __restrict__ em_lin)
{
    __shared__ float tile[32][33];
    const int jb = blockIdx.x * 32;
    const int sb = blockIdx.y * 32;
    const int cc = threadIdx.x & 31;
    const int rr = threadIdx.x >> 5;
#pragma unroll
    for (int i = 0; i < 4; ++i) {
        int r = rr + 8 * i;
        tile[r][cc] = emT[(size_t)(sb + r) * (NB * NT) + jb + cc];
    }
    __syncthreads();
#pragma unroll
    for (int i = 0; i < 4; ++i) {
        int r = rr + 8 * i;
        int s = sb + cc;
        int ps = (s & ~127) | ((s & 15) << 3) | ((s >> 4) & 7);
        em_lin[(size_t)(jb + r) * NS + ps] = tile[cc][r];
    }
}

// ---------------------------------------------------------------------------
// K2a: zscale[k] = 1024 / sum_d exp(tm[k][d])
// ---------------------------------------------------------------------------
__global__ __launch_bounds__(64) void k_z(
    const float* __restrict__ tm, float* __restrict__ zscale)
{
    const int k    = blockIdx.x;
    const int lane = threadIdx.x;
    const float* row = tm + (size_t)k * NS;

    float4 a = ((const float4*)row)[lane * 2];
    float4 b = ((const float4*)row)[lane * 2 + 1];
    float sum = ((__expf(a.x) + __expf(a.y)) + (__expf(a.z) + __expf(a.w)))
              + ((__expf(b.x) + __expf(b.y)) + (__expf(b.z) + __expf(b.w)));
#pragma unroll
    for (int off = 32; off; off >>= 1) sum += __shfl_down(sum, off);
    if (lane == 0) zscale[k] = 1024.0f / sum;
}

// ---------------------------------------------------------------------------
// K2b: PT[d][k] = exp(tm[k][d]) * zscale[k], e4m3 fp8, LDS-transposed tiles.
// ---------------------------------------------------------------------------
__global__ __launch_bounds__(256) void k_pt2(
    const float* __restrict__ tm, const float* __restrict__ zscale,
    unsigned char* __restrict__ PT)
{
    __shared__ float tile[64][65];
    __shared__ float zs[64];
    const int kb  = blockIdx.x * 64;
    const int db  = blockIdx.y * 64;
    const int tid = threadIdx.x;
    const int c   = tid & 63;
    const int r0  = tid >> 6;

    if (tid < 64) zs[tid] = zscale[kb + tid];
#pragma unroll
    for (int i = 0; i < 16; ++i) {
        int r = r0 + 4 * i;
        tile[r][c] = tm[(size_t)(kb + r) * NS + db + c];
    }
    __syncthreads();

    const int d  = tid >> 2;
    const int ks = (tid & 3) * 16;
    unsigned px[4];
#pragma unroll
    for (int gq = 0; gq < 4; ++gq) {
        int k0 = ks + gq * 4;
        px[gq] = pack4_e4m3(__expf(tile[k0 + 0][d]) * zs[k0 + 0],
                            __expf(tile[k0 + 1][d]) * zs[k0 + 1],
                            __expf(tile[k0 + 2][d]) * zs[k0 + 2],
                            __expf(tile[k0 + 3][d]) * zs[k0 + 3]);
    }
    uint4 o; o.x = px[0]; o.y = px[1]; o.z = px[2]; o.w = px[3];
    *(uint4*)(PT + (size_t)(db + d) * NS + kb + ks) = o;
}

// ---------------------------------------------------------------------------
// K3 v12: 4-wave / 1-wave-per-SIMD layout.
//   Counters showed MfmaUtil(38.8%) + VALUBusy(40.6%) ~ mutually exclusive:
//   the barrier convoys all waves into the same phase, so the matrix pipe
//   idles during the whole quantize+barrier+LDS window, and at 2 waves/SIMD
//   that window's VALU is 2x contended.  Per-SIMD MFMA count (32/step) is
//   matrix-determined and wave-layout-invariant, but the EXPOSED window
//   shrinks at 1 wave/SIMD: solo quantize, 4-wave barrier, half the LDS
//   burst.  Each wave owns 128 output states (8 nt x 4 kt = 32 MFMAs);
//   B regs = 256 VGPR -- fits the 512-VGPR budget at occupancy 1
//   (__launch_bounds__(256,1); v8's spill was the 1024-thr 128-cap).
//   Consumer-side Ew layout identical (uint4-cols = 8w+nt, same 0..31).
//   Exponent table gains per-32-block granularity [j=lqblk][batch][kt]
//   (nt-pair maxes) -- natively supported by the MFMA scale operand;
//   numerics stay power-of-2-exact (lagged M̂ scheme unchanged).
// ---------------------------------------------------------------------------
__global__ __launch_bounds__(256, 1) void k_scan(
    const float* __restrict__ em_lin, const unsigned char* __restrict__ PT,
    const float* __restrict__ p, float* __restrict__ out)
{
    const int bb  = blockIdx.x;        // batch group: global batches bb*4+0..3
    const int tid = threadIdx.x;
    const int w   = tid >> 6;          // wave 0..3
    const int l   = tid & 63;          // lane
    const int lc  = l & 15;            // state-col within 16-tile
    const int lq  = l >> 4;            // local batch 0..3

    __shared__ __align__(16) unsigned Ew[2][16 * 128];   // 16 KB, double-buffered
    __shared__ __align__(4) unsigned char wmE[2][64];    // [(j*4+b)*4 + kt]
    __shared__ __align__(4) unsigned char mbuf[2][4];    // lagged M̂, byte b = batch b
    __shared__ float    wm2[4][4];
    __shared__ float    sbuf[4];

    // ---- load B fragments (P, once): row j = 128w + 16nt + lc ----
    v8i B[8][4];
#pragma unroll
    for (int nt = 0; nt < 8; ++nt) {
#pragma unroll
        for (int kt = 0; kt < 4; ++kt) {
            const uint4* src = (const uint4*)(PT + (size_t)(128 * w + 16 * nt + lc) * NS + kt * 128 + lq * 32);
            v8i bb8;
            *(uint4*)&bb8       = src[0];
            *((uint4*)&bb8 + 1) = src[1];
            B[nt][kt] = bb8;
        }
    }

    // ---- zero both Ew buffers ONCE (zero rows are never rewritten) ----
    {
        uint4 zz; zz.x = 0; zz.y = 0; zz.z = 0; zz.w = 0;
        uint4* z = (uint4*)&Ew[0][0];
#pragma unroll
        for (int i = 0; i < 8; ++i) z[tid + 256 * i] = zz;
    }

    // ---- prior softmax denominator ----
    float zp = 0.f;
#pragma unroll
    for (int i = 0; i < 8; ++i) zp += __expf(p[l * 8 + i]);
    DPPADD(zp, 0x128); DPPADD(zp, 0x124); DPPADD(zp, 0xB1); DPPADD(zp, 0x4E);
    float Zp = __int_as_float(__builtin_amdgcn_readlane(__float_as_int(zp), 0))
             + __int_as_float(__builtin_amdgcn_readlane(__float_as_int(zp), 16))
             + __int_as_float(__builtin_amdgcn_readlane(__float_as_int(zp), 32))
             + __int_as_float(__builtin_amdgcn_readlane(__float_as_int(zp), 48));
    const float invZp = 1.0f / Zp;

    const int dbase = 128 * w + lc;          // state for nt: dbase + 16*nt
    const int gb    = bb * 4 + lq;           // global batch of this thread

    // ---- alpha_0 (linear; 2^-18 embedded in em_lin -> shift starts at 18) ----
    // permuted em layout: thread's 8 states contiguous at 128w + lc*8
    const float* epb0 = em_lin + (size_t)gb * (NT * NS) + (128 * w + lc * 8);
    v4f e0a = ((const v4f*)epb0)[0];
    v4f e0b = ((const v4f*)epb0)[1];
    float alpha[8];
#pragma unroll
    for (int nt = 0; nt < 8; ++nt)
        alpha[nt] = __expf(p[dbase + 16 * nt]) * invZp * (nt < 4 ? e0a[nt] : e0b[nt - 4]);

    int gsum = 18;
    const unsigned sel1 = (l & 1) ? 0x07030501u : 0x02060004u;
    const unsigned sel2 = (l & 2) ? 0x07060302u : 0x01000504u;
    const int mrow = 4 * lq + (l & 3);

    // hoisted, t-invariant A-read uint4-indices (UNCHANGED formula) and
    // Ew write dword-indices (producer uint4-col = 8w + nt, 0..31)
    int aidx[8];
#pragma unroll
    for (int kt = 0; kt < 4; ++kt) {
#pragma unroll
        for (int c = 0; c < 2; ++c)
            aidx[kt * 2 + c] = lc * 32 + (((kt * 8 + lq * 2 + c) ^ lc) & 31);
    }
    int widx[8];
#pragma unroll
    for (int nt = 0; nt < 8; ++nt)
        widx[nt] = mrow * 128 + ((((8 * w + nt) ^ mrow) & 31) << 2) + (lc >> 2);

    // A-row held by this lane is row lc -> batch bA = lc>>2.
    const int bA = lc >> 2;
    const unsigned shA = (unsigned)(bA << 3);
    const unsigned shQ = (unsigned)(lq << 3);
    const int wexp_r = (lq * 4 + bA) * 4;   // consumer scale dword offset
    const bool real = (l & 3) == 0;          // lane holds a real (nonzero) A-row

    const float* epb = epb0 + NS;            // emission pointer, stepped by NS

    // ---- seed wmE[1]/mbuf[1] with E(0)/M(0) ----
    {
        float m0 = fmaxf(alpha[0], alpha[1]), m1 = fmaxf(alpha[2], alpha[3]);
        float m2 = fmaxf(alpha[4], alpha[5]), m3 = fmaxf(alpha[6], alpha[7]);
        DPPMAX(m0, 0x128); DPPMAX(m1, 0x128); DPPMAX(m2, 0x128); DPPMAX(m3, 0x128);
        DPPMAX(m0, 0x124); DPPMAX(m1, 0x124); DPPMAX(m2, 0x124); DPPMAX(m3, 0x124);
        DPPMAX(m0, 0xB1);  DPPMAX(m1, 0xB1);  DPPMAX(m2, 0xB1);  DPPMAX(m3, 0xB1);
        DPPMAX(m0, 0x4E);  DPPMAX(m1, 0x4E);  DPPMAX(m2, 0x4E);  DPPMAX(m3, 0x4E);
        unsigned E0 = __float_as_uint(m0) >> 23; E0 = E0 > 1u ? E0 : 1u;
        unsigned E1 = __float_as_uint(m1) >> 23; E1 = E1 > 1u ? E1 : 1u;
        unsigned E2 = __float_as_uint(m2) >> 23; E2 = E2 > 1u ? E2 : 1u;
        unsigned E3 = __float_as_uint(m3) >> 23; E3 = E3 > 1u ? E3 : 1u;
        if (lc == 0) {
            wmE[1][(0 * 4 + lq) * 4 + w] = (unsigned char)E0;
            wmE[1][(1 * 4 + lq) * 4 + w] = (unsigned char)E1;
            wmE[1][(2 * 4 + lq) * 4 + w] = (unsigned char)E2;
            wmE[1][(3 * 4 + lq) * 4 + w] = (unsigned char)E3;
        }
    }
    __syncthreads();
    if (tid < 4) {
        const unsigned u0 = *(const unsigned*)&wmE[1][tid * 4];
        const unsigned u1 = *(const unsigned*)&wmE[1][16 + tid * 4];
        const unsigned u2 = *(const unsigned*)&wmE[1][32 + tid * 4];
        const unsigned u3 = *(const unsigned*)&wmE[1][48 + tid * 4];
        mbuf[1][tid] = (unsigned char)bytemax8(bytemax8(u0, u1), bytemax8(u2, u3));
    }
    // (benign race: t=1 rewrites wmE[1] with the identical E(0) bytes)

    const v4f CZ = {0.f, 0.f, 0.f, 0.f};

    // hoisted zero A fragments; masked-out lanes keep zeros forever
    v8i A[4];
#pragma unroll
    for (int kt = 0; kt < 4; ++kt)
#pragma unroll
        for (int i = 0; i < 8; ++i) A[kt][i] = 0;

    for (int t = 1; t < NT; ++t) {
        const int buf = t & 1;
        unsigned* EwB = &Ew[buf][0];

        // ---- per-32-block WAVE-LOCAL maxes (nt-pairs; rows of 16 = batch) ----
        float m0 = fmaxf(alpha[0], alpha[1]), m1 = fmaxf(alpha[2], alpha[3]);
        float m2 = fmaxf(alpha[4], alpha[5]), m3 = fmaxf(alpha[6], alpha[7]);
        DPPMAX(m0, 0x128); DPPMAX(m1, 0x128); DPPMAX(m2, 0x128); DPPMAX(m3, 0x128);
        DPPMAX(m0, 0x124); DPPMAX(m1, 0x124); DPPMAX(m2, 0x124); DPPMAX(m3, 0x124);
        DPPMAX(m0, 0xB1);  DPPMAX(m1, 0xB1);  DPPMAX(m2, 0xB1);  DPPMAX(m3, 0xB1);
        DPPMAX(m0, 0x4E);  DPPMAX(m1, 0x4E);  DPPMAX(m2, 0x4E);  DPPMAX(m3, 0x4E);
        unsigned Ej[4];
        Ej[0] = __float_as_uint(m0) >> 23; Ej[0] = Ej[0] > 1u ? Ej[0] : 1u;
        Ej[1] = __float_as_uint(m1) >> 23; Ej[1] = Ej[1] > 1u ? Ej[1] : 1u;
        Ej[2] = __float_as_uint(m2) >> 23; Ej[2] = Ej[2] > 1u ? Ej[2] : 1u;
        Ej[3] = __float_as_uint(m3) >> 23; Ej[3] = Ej[3] > 1u ? Ej[3] : 1u;
        float scj[4];
#pragma unroll
        for (int j = 0; j < 4; ++j)
            scj[j] = __uint_as_float((261u - Ej[j]) << 23);   // 2^(134-E)

        // ---- e -> fp8 (block-local scale), DPP 4x4 byte transpose ----
        unsigned dwv[8];
#pragma unroll
        for (int nt = 0; nt < 8; ++nt) {
            unsigned dw = pack1_e4m3(alpha[nt] * scj[nt >> 1]);
            int tmp = __builtin_amdgcn_mov_dpp((int)dw, 0xB1, 0xF, 0xF, true);
            dw = __builtin_amdgcn_perm(dw, (unsigned)tmp, sel1);
            tmp = __builtin_amdgcn_mov_dpp((int)dw, 0x4E, 0xF, 0xF, true);
            dw = __builtin_amdgcn_perm(dw, (unsigned)tmp, sel2);
            dwv[nt] = dw;
        }
        if (real) {
#pragma unroll
            for (int nt = 0; nt < 8; ++nt) EwB[widx[nt]] = dwv[nt];
        }
        if (lc == 0) {
            wmE[buf][(0 * 4 + lq) * 4 + w] = (unsigned char)Ej[0];
            wmE[buf][(1 * 4 + lq) * 4 + w] = (unsigned char)Ej[1];
            wmE[buf][(2 * 4 + lq) * 4 + w] = (unsigned char)Ej[2];
            wmE[buf][(3 * 4 + lq) * 4 + w] = (unsigned char)Ej[3];
        }
        __syncthreads();                                    // the ONLY barrier

        // ---- (1) scale-exponent reads FIRST ----
        const unsigned dwE = *(const unsigned*)&wmE[buf][wexp_r];
        const unsigned mdw = *(const unsigned*)&mbuf[buf][0];

        // ---- (2) emission VMEM loads (latency hidden under MFMA phase) ----
        v4f epfa = ((const v4f*)epb)[0];
        v4f epfb = ((const v4f*)epb)[1];
        epb += NS;

        // ---- (3) A fragments from LDS (masked to real lanes) ----
        if (real) {
            const uint4* eb4 = (const uint4*)EwB;
#pragma unroll
            for (int kt = 0; kt < 4; ++kt) {
                *(uint4*)&A[kt]       = eb4[aidx[kt * 2 + 0]];
                *((uint4*)&A[kt] + 1) = eb4[aidx[kt * 2 + 1]];
            }
        }

        // ---- (4) scA VALU (overlaps A-read returns) ----
        const int MhA = (int)((mdw >> shA) & 255u);
        const int MhQ = (int)((mdw >> shQ) & 255u);
        gsum += MhQ - 126;

        const int base = 127 - MhA;
        int s0 = (int)(dwE & 255u) + base;         s0 = s0 < 0 ? 0 : (s0 > 254 ? 254 : s0);
        int s1 = (int)((dwE >> 8) & 255u) + base;  s1 = s1 < 0 ? 0 : (s1 > 254 ? 254 : s1);
        int s2 = (int)((dwE >> 16) & 255u) + base; s2 = s2 < 0 ? 0 : (s2 > 254 ? 254 : s2);
        int s3 = (int)(dwE >> 24) + base;          s3 = s3 < 0 ? 0 : (s3 > 254 ? 254 : s3);
        const int scA[4] = { s0 * 0x01010101, s1 * 0x01010101,
                             s2 * 0x01010101, s3 * 0x01010101 };

        // ---- (5) MFMA: 8 independent nt-chains of depth 4 ----
        v4f C[8];
#pragma unroll
        for (int nt = 0; nt < 8; ++nt)
            C[nt] = __builtin_amdgcn_mfma_scale_f32_16x16x128_f8f6f4(
                        A[0], B[nt][0], CZ, 0, 0, 0, scA[0], 0, 0x7F7F7F7F);
#pragma unroll
        for (int kt = 1; kt < 4; ++kt)
#pragma unroll
            for (int nt = 0; nt < 8; ++nt)
                C[nt] = __builtin_amdgcn_mfma_scale_f32_16x16x128_f8f6f4(
                            A[kt], B[nt][kt], C[nt], 0, 0, 0, scA[kt], 0, 0x7F7F7F7F);

        // ---- (6) mbuf maintenance AFTER the MFMAs: mbuf[buf^1] = M(t) ----
        if (tid < 4) {
            const unsigned u0 = *(const unsigned*)&wmE[buf][tid * 4];
            const unsigned u1 = *(const unsigned*)&wmE[buf][16 + tid * 4];
            const unsigned u2 = *(const unsigned*)&wmE[buf][32 + tid * 4];
            const unsigned u3 = *(const unsigned*)&wmE[buf][48 + tid * 4];
            mbuf[buf ^ 1][tid] = (unsigned char)bytemax8(bytemax8(u0, u1), bytemax8(u2, u3));
        }

        // ---- (7) alpha update (linear); batch lq = C-row 4*lq = reg 0 ----
#pragma unroll
        for (int nt = 0; nt < 8; ++nt)
            alpha[nt] = C[nt][0] * (nt < 4 ? epfa[nt] : epfb[nt - 4]);
    }

    // ---- final: per-batch logsumexp over states ----
    {
        float sm = ((alpha[0] + alpha[1]) + (alpha[2] + alpha[3]))
                 + ((alpha[4] + alpha[5]) + (alpha[6] + alpha[7]));
        DPPADD(sm, 0x128); DPPADD(sm, 0x124); DPPADD(sm, 0xB1); DPPADD(sm, 0x4E);
        if (lc == 0) wm2[w][lq] = sm;
        if (w == 0 && lc == 0) sbuf[lq] = (float)gsum;
    }
    __syncthreads();
    if (tid < 4) {
        float s8 = (wm2[0][tid] + wm2[1][tid]) + (wm2[2][tid] + wm2[3][tid]);
        float L2 = __log2f(s8) + sbuf[tid];
        atomicAdd(out, -(0.693147180559945f / 16.0f) * L2);
    }
}

// ---------------------------------------------------------------------------
extern "C" void kernel_launch(void* const* d_in, const int* in_sizes, int n_in,
                              void* d_out, int out_size, void* d_ws, size_t ws_size,
                              hipStream_t stream)
{
    const int*   ids = (const int*)d_in[0];   // [16][128]
    const float* em  = (const float*)d_in[1]; // [512][32000]
    const float* tm  = (const float*)d_in[2]; // [512][512]
    const float* p   = (const float*)d_in[3]; // [512]
    float* out = (float*)d_out;

    float*          em_lin = (float*)d_ws;
    unsigned char*  PT     = (unsigned char*)d_ws + ((size_t)4 << 20);
    float*          zscale = (float*)((unsigned char*)d_ws + ((size_t)4 << 20) + ((size_t)256 << 10));
    float*          emT    = (float*)((unsigned char*)d_ws + ((size_t)4 << 20) + ((size_t)512 << 10));

    hipMemsetAsync(d_out, 0, sizeof(float), stream);

    k_emtok_T<<<NS, 256, 0, stream>>>(em, ids, emT);
    k_tr<<<dim3(64, 16), 256, 0, stream>>>(emT, em_lin);
    k_z<<<NS, 64, 0, stream>>>(tm, zscale);
    k_pt2<<<dim3(8, 8), 256, 0, stream>>>(tm, zscale, PT);
    k_scan<<<4, 256, 0, stream>>>(em_lin, PT, p, out);
}